// Round 10
// baseline (125.605 us; speedup 1.0000x reference)
//
#include <hip/hip_runtime.h>
#include <stdint.h>

// SpatialShiftConvBlock (B=8,T=64,N=21,C=128,F=256):
//   xs[b,t,n,c] = x[b,t,(n - c%21) mod 21, c]       (per-channel circular roll)
//   y  = xs @ W (+ b == 0, and bias cancels in BN anyway)
//   y  = (y - mean)*rsqrt(var + 1e-3)*gamma + beta  (BN training stats over B,T,N)
//   out = relu(y)  (float32 output)
//
// R38: ONE fused kernel. R37 (91.4us) still paid a 33MB y round-trip
// (write pre-norm + read + write) plus k_prep/k_zero launches, all because BN
// stats are a grid-wide dependency. Here: 512 blocks, all co-resident
// (launch_bounds(256,2) -> >=2 blocks/CU capacity; LDS 10.75KB), hand-rolled
// grid barrier via device-scope atomics (G16 pattern: threadfence release +
// atomic ctr + agent-scope atomic loads). acc stays in VGPRs across the
// barrier; y is written ONCE, post-BN. W->bf16 B-frags converted per-block
// from raw W (no cross-block staging; 128KB/block from L2).
//  - MFMA path identical to R37 (passed, absmax 0.031): A bf16 [32][136] LDS
//    pre-shifted, rows 21..31 zero; frag maps A: row=l&15,k=(l>>4)*8+j;
//    B: col=l&15 same k; C/D: col=l&15,row=(l>>4)*4+reg.
//  - ws: [0:256] ch sums, [256:512] ch sumsqs, [512] barrier ctr; zeroed by
//    hipMemsetAsync (2KB, graph-capturable). fillBufferAligned (~42us
//    harness ws re-poison) is an unconditional tax we cannot remove.

#define NPOS 21
#define CIN  128
#define FOUT 256
#define BT   512            // B*T = grid
#define M_TOTAL 10752       // BT*NPOS
#define BN_EPS 1e-3f
#define AROW 136            // A LDS row stride in bf16 (272B: 16B-aligned)

typedef short v8s __attribute__((ext_vector_type(8)));   // 8 bf16 (4 VGPR)
typedef float v4f __attribute__((ext_vector_type(4)));   // 4 f32 acc

__device__ __forceinline__ uint16_t f2bf_rne(float f) {
    uint32_t u = __builtin_bit_cast(uint32_t, f);
    u += 0x7FFFu + ((u >> 16) & 1u);                     // round-nearest-even
    return (uint16_t)(u >> 16);
}

__global__ __launch_bounds__(256, 2) void k_fused(const float* __restrict__ x,
                                                  const float* __restrict__ W,
                                                  const float* __restrict__ gamma,
                                                  const float* __restrict__ beta,
                                                  float* __restrict__ y,
                                                  float* ws)
{
    __shared__ uint16_t asB[32 * AROW];    // 8.7 KB bf16 A, pre-shifted
    __shared__ float scL[FOUT];            // sums, then scale
    __shared__ float bsL[FOUT];            // sumsqs, then bias

    const int bt = blockIdx.x;
    const int t  = threadIdx.x;

    // ---------- Phase A: stage A-slab (LDS) + convert W->B-frags (regs) ----
    for (int i = t; i < 704; i += 256) {   // zero pad rows 21..31
        int r  = 21 + (i >> 6);
        int c2 = (i & 63) << 1;
        *(uint32_t*)&asB[r * AROW + c2] = 0u;
    }
    const float* xin = x + (size_t)bt * (NPOS * CIN);
    for (int i = t; i < NPOS * CIN; i += 256) {
        float v = xin[i];                  // fully coalesced f32 load
        int r = i >> 7;                    // i = r*128 + c
        int c = i & (CIN - 1);
        int s = c % NPOS;
        int n = r + s; if (n >= NPOS) n -= NPOS;
        asB[n * AROW + c] = f2bf_rne(v);   // asB[n][c] == bf16(xs[n][c])
    }

    const int w     = t >> 6;              // wave id -> channel group w*64
    const int l     = t & 63;
    const int row16 = l & 15;
    const int koct  = l >> 4;

    v8s bfr[4][4];                         // this lane's 16 B fragments
    #pragma unroll
    for (int nt = 0; nt < 4; nt++) {
        const int col = (w * 4 + nt) * 16 + row16;
        #pragma unroll
        for (int ks = 0; ks < 4; ks++) {
            const int kb = ks * 32 + koct * 8;
            uint32_t d[4];
            #pragma unroll
            for (int p = 0; p < 4; p++) {
                uint32_t lo = f2bf_rne(W[(size_t)(kb + 2 * p    ) * FOUT + col]);
                uint32_t hi = f2bf_rne(W[(size_t)(kb + 2 * p + 1) * FOUT + col]);
                d[p] = lo | (hi << 16);
            }
            uint4 u = make_uint4(d[0], d[1], d[2], d[3]);
            bfr[nt][ks] = __builtin_bit_cast(v8s, u);
        }
    }
    __syncthreads();

    // ---------- Phase B: MFMA + per-channel partial sums ----------
    v4f acc[2][4];
    #pragma unroll
    for (int m = 0; m < 2; m++)
        #pragma unroll
        for (int nt = 0; nt < 4; nt++) acc[m][nt] = (v4f){0.f, 0.f, 0.f, 0.f};

    #pragma unroll
    for (int m = 0; m < 2; m++) {
        v8s afr[4];
        #pragma unroll
        for (int ks = 0; ks < 4; ks++)     // ds_read_b128, 16B-aligned
            afr[ks] = *(const v8s*)&asB[(m * 16 + row16) * AROW + ks * 32 + koct * 8];
        #pragma unroll
        for (int ks = 0; ks < 4; ks++)
            #pragma unroll
            for (int nt = 0; nt < 4; nt++)
                acc[m][nt] = __builtin_amdgcn_mfma_f32_16x16x32_bf16(
                                 afr[ks], bfr[nt][ks], acc[m][nt], 0, 0, 0);
    }

    #pragma unroll
    for (int nt = 0; nt < 4; nt++) {
        float s = 0.f, q = 0.f;
        #pragma unroll
        for (int m = 0; m < 2; m++)
            #pragma unroll
            for (int rg = 0; rg < 4; rg++) {
                float v = acc[m][nt][rg];  // pad rows contribute exactly 0
                s += v; q += v * v;
            }
        s += __shfl_xor(s, 16); s += __shfl_xor(s, 32);
        q += __shfl_xor(q, 16); q += __shfl_xor(q, 32);
        if (l < 16) {
            scL[w * 64 + nt * 16 + l] = s;
            bsL[w * 64 + nt * 16 + l] = q;
        }
    }
    __syncthreads();
    atomicAdd(ws + t, scL[t]);             // 512 adds/address over the grid
    atomicAdd(ws + FOUT + t, bsL[t]);
    __threadfence();                       // release my atomics
    __syncthreads();

    // ---------- grid-wide barrier (all 512 blocks co-resident) ----------
    if (t == 0) {
        atomicAdd((unsigned int*)(ws + 512), 1u);
        while (__hip_atomic_load((unsigned int*)(ws + 512),
                                 __ATOMIC_RELAXED, __HIP_MEMORY_SCOPE_AGENT)
               < (unsigned int)gridDim.x)
            __builtin_amdgcn_s_sleep(2);
    }
    __syncthreads();

    // ---------- Phase C: stats -> scale/bias, normalize in regs, store ----
    {
        float s = __hip_atomic_load(ws + t, __ATOMIC_RELAXED,
                                    __HIP_MEMORY_SCOPE_AGENT);
        float q = __hip_atomic_load(ws + FOUT + t, __ATOMIC_RELAXED,
                                    __HIP_MEMORY_SCOPE_AGENT);
        const float invM = 1.0f / (float)M_TOTAL;
        float mean = s * invM;
        float var  = fmaf(-mean, mean, q * invM);
        float sc   = rsqrtf(var + BN_EPS) * gamma[t];
        scL[t] = sc;
        bsL[t] = beta[t] - mean * sc;
    }
    __syncthreads();

    float* yout = y + (size_t)bt * (NPOS * FOUT);
    #pragma unroll
    for (int nt = 0; nt < 4; nt++) {
        const int ch = w * 64 + nt * 16 + row16;
        const float sc = scL[ch];
        const float bs = bsL[ch];
        #pragma unroll
        for (int m = 0; m < 2; m++)
            #pragma unroll
            for (int rg = 0; rg < 4; rg++) {
                int gr = m * 16 + koct * 4 + rg;   // C/D: col=row16, row=koct*4+rg
                if (gr < NPOS)
                    yout[(size_t)gr * FOUT + ch] =
                        fmaxf(fmaf(acc[m][nt][rg], sc, bs), 0.0f);
            }
    }
}

// Template-named symbol kept defined (harness-compat; not launched).
extern "C" __global__ void SpatialShiftConvBlock_71923522339050_kernel() {}

extern "C" void kernel_launch(void* const* d_in, const int* in_sizes, int n_in,
                              void* d_out, int out_size, void* d_ws, size_t ws_size,
                              hipStream_t stream) {
    float* y  = (float*)d_out;             // FLOAT32 output
    float* ws = (float*)d_ws;              // sums | sumsqs | barrier ctr
    hipMemsetAsync(ws, 0, 516 * sizeof(float), stream);
    k_fused<<<BT, 256, 0, stream>>>((const float*)d_in[0], (const float*)d_in[1],
                                    (const float*)d_in[3], (const float*)d_in[4],
                                    y, ws);
}